// Round 7
// baseline (1238.855 us; speedup 1.0000x reference)
//
#include <hip/hip_runtime.h>
#include <math.h>

#define DIM    256
#define IDIM   64
#define HEADS  4
#define NSEQ   256
#define SEQLEN 256
#define NTOK   (NSEQ * SEQLEN)
#define EPSLN  1e-5f

typedef __attribute__((ext_vector_type(8))) short bf16x8s;
typedef __attribute__((ext_vector_type(4))) float f32x4;

union BF8 { bf16x8s v; unsigned short u[8]; };

__device__ __forceinline__ float bf2f(unsigned short u) {
    union { unsigned int i; float f; } v; v.i = ((unsigned int)u) << 16; return v.f;
}
__device__ __forceinline__ unsigned short f2bf(float f) {
    union { float f; unsigned int i; } v; v.f = f;
    unsigned int x = v.i;
    return (unsigned short)((x + 0x7fffu + ((x >> 16) & 1u)) >> 16);
}

// Packed weights: 8 slots (pass*4 + {wq,wk,wv,wo}), each [16 nt][8 kt][64 lanes] x bf16x8
__device__ bf16x8s g_wpk[8][8192];

// =====================================================================
// Pack ALL weights once. grid=(32,8): y = slot (pass*4+m).
// B-fragment layout: lane l holds B[k=kt*32+8*(l>>4)+j][n=nt*16+(l&15)]
// Wo (m=3): packed k index is h-major (h*64+d); source row is d-major (d*4+h).
// =====================================================================
__global__ __launch_bounds__(256) void wpack_all_kernel(
    const float* __restrict__ Wq_i, const float* __restrict__ Wkv_i,
    const float* __restrict__ Wo_i,
    const float* __restrict__ Wq_j, const float* __restrict__ Wkv_j,
    const float* __restrict__ Wo_j)
{
    const int slot = blockIdx.y;
    const int pass = slot >> 2, m = slot & 3;
    const float* W; int ldw, col0, perm;
    if (m == 0)      { W = pass ? Wq_j  : Wq_i;  ldw = 256; col0 = 0;   perm = 0; }
    else if (m == 1) { W = pass ? Wkv_j : Wkv_i; ldw = 512; col0 = 0;   perm = 0; }
    else if (m == 2) { W = pass ? Wkv_j : Wkv_i; ldw = 512; col0 = 256; perm = 0; }
    else             { W = pass ? Wo_j  : Wo_i;  ldw = 256; col0 = 0;   perm = 1; }

    const int gtile = blockIdx.x * 4 + (threadIdx.x >> 6);   // nt*8+kt, 128 tiles
    const int l = threadIdx.x & 63;
    const int nt = gtile >> 3, kt = gtile & 7;
    const int n = nt * 16 + (l & 15);
    const int k0 = kt * 32 + (l >> 4) * 8;
    BF8 o;
#pragma unroll
    for (int j = 0; j < 8; ++j) {
        int k = k0 + j;
        int src = perm ? ((k & 63) * 4 + (k >> 6)) : k;
        o.u[j] = f2bf(W[(size_t)src * ldw + col0 + n]);
    }
    g_wpk[slot][(size_t)gtile * 64 + l] = o.v;
}

// =====================================================================
// Fused LN + QKV GEMM (f32 activations, hi+lo bf16 MFMA) + RoPE + repack.
// Block = 32 tokens (one seq). 4 waves; wave w owns n-tiles [w*12, w*12+12).
// LDS 37.9 KB: phase1 xn[32][264]+params[1024]; phase2 C chunks 32x261 (q,k,v serially).
// =====================================================================
#define XLD  264
#define GOFF (32 * XLD)           // 8448
#define CLD2 261

__global__ __launch_bounds__(256, 3) void lnqkv_kernel(
    const float* __restrict__ x,
    const float* __restrict__ sin_t, const float* __restrict__ cos_t,
    const float* __restrict__ ga, const float* __restrict__ ba,
    const float* __restrict__ gb, const float* __restrict__ bb,
    bf16x8s* __restrict__ qo, bf16x8s* __restrict__ ko, bf16x8s* __restrict__ vo,
    int pass)
{
    __shared__ float smf[32 * XLD + 1024];   // 37,888 B

    const int tid = threadIdx.x;
    const int l = tid & 63, w = tid >> 6;
    const int lr = l & 15, lk = l >> 4;
    const int t0 = blockIdx.x * 32;
    const int seq = t0 >> 8;
    const int pos0 = t0 & 255;
    const int wbase = pass * 4;

    // ---- stage x rows + LN params ----
    for (int r = 0; r < 32; ++r) {
        int t = t0 + r;
        int row = (pass == 0) ? t : ((t & 255) * NSEQ + (t >> 8));
        smf[r * XLD + tid] = x[(size_t)row * DIM + tid];
    }
    smf[GOFF + 0 * 256 + tid] = ga[tid];
    smf[GOFF + 1 * 256 + tid] = ba[tid];
    smf[GOFF + 2 * 256 + tid] = gb[tid];
    smf[GOFF + 3 * 256 + tid] = bb[tid];
    __syncthreads();

    // ---- LN stats (8 threads/row), normalize in place ----
    {
        const int r = tid >> 3, sub = tid & 7;
        float s1 = 0.f, s2 = 0.f;
        for (int m = 0; m < 32; ++m) { float v = smf[r * XLD + sub + 8 * m]; s1 += v; s2 += v * v; }
        for (int off = 1; off < 8; off <<= 1) {
            s1 += __shfl_xor(s1, off, 64);
            s2 += __shfl_xor(s2, off, 64);
        }
        float mu = s1 * (1.f / 256.f);
        float var = s2 * (1.f / 256.f) - mu * mu;
        float rstd = rsqrtf(var + EPSLN);
        for (int m = 0; m < 32; ++m) {
            int d = sub + 8 * m;
            smf[r * XLD + d] = (smf[r * XLD + d] - mu) * rstd;
        }
    }
    __syncthreads();

    // ---- K-loop: acc[2 m-frags][12 n-frags], hi+lo A ----
    f32x4 acc[2][12];
#pragma unroll
    for (int mf = 0; mf < 2; ++mf)
#pragma unroll
        for (int nf = 0; nf < 12; ++nf) { f32x4 z = {0.f, 0.f, 0.f, 0.f}; acc[mf][nf] = z; }

    const int nt0 = w * 12;
    const bool needA = (nt0 < 16);
    const bool needB = (nt0 + 11 >= 16);

    for (int ks = 0; ks < 8; ++ks) {
        const int c0 = ks * 32 + lk * 8;
        float gav[8], bav[8], gbv[8], bbv[8];
#pragma unroll
        for (int j = 0; j < 8; ++j) {
            gav[j] = smf[GOFF + 0 * 256 + c0 + j];
            bav[j] = smf[GOFF + 1 * 256 + c0 + j];
            gbv[j] = smf[GOFF + 2 * 256 + c0 + j];
            bbv[j] = smf[GOFF + 3 * 256 + c0 + j];
        }
        BF8 ahA[2], alA[2], ahB[2], alB[2];
#pragma unroll
        for (int mf = 0; mf < 2; ++mf) {
            const float* xr = &smf[(mf * 16 + lr) * XLD + c0];
            float xv[8];
#pragma unroll
            for (int j = 0; j < 8; ++j) xv[j] = xr[j];
            if (needA) {
#pragma unroll
                for (int j = 0; j < 8; ++j) {
                    float a = xv[j] * gav[j] + bav[j];
                    unsigned short hi = f2bf(a);
                    ahA[mf].u[j] = hi;
                    alA[mf].u[j] = f2bf(a - bf2f(hi));
                }
            }
            if (needB) {
#pragma unroll
                for (int j = 0; j < 8; ++j) {
                    float a = xv[j] * gbv[j] + bbv[j];
                    unsigned short hi = f2bf(a);
                    ahB[mf].u[j] = hi;
                    alB[mf].u[j] = f2bf(a - bf2f(hi));
                }
            }
        }
#pragma unroll
        for (int nf = 0; nf < 12; ++nf) {
            const int ntg = nt0 + nf;      // wave-uniform
            const bf16x8s b = g_wpk[wbase + (ntg >> 4)][((size_t)((ntg & 15) * 8 + ks)) * 64 + l];
            if (ntg < 16) {
#pragma unroll
                for (int mf = 0; mf < 2; ++mf) {
                    acc[mf][nf] = __builtin_amdgcn_mfma_f32_16x16x32_bf16(alA[mf].v, b, acc[mf][nf], 0, 0, 0);
                    acc[mf][nf] = __builtin_amdgcn_mfma_f32_16x16x32_bf16(ahA[mf].v, b, acc[mf][nf], 0, 0, 0);
                }
            } else {
#pragma unroll
                for (int mf = 0; mf < 2; ++mf) {
                    acc[mf][nf] = __builtin_amdgcn_mfma_f32_16x16x32_bf16(alB[mf].v, b, acc[mf][nf], 0, 0, 0);
                    acc[mf][nf] = __builtin_amdgcn_mfma_f32_16x16x32_bf16(ahB[mf].v, b, acc[mf][nf], 0, 0, 0);
                }
            }
        }
    }
    __syncthreads();   // all waves done reading xn/params

    // ---- three C chunks (q, k, v): write f32 C, then epilogue ----
    for (int c = 0; c < 3; ++c) {
        // write this wave's n-tiles belonging to chunk c
#pragma unroll
        for (int nf = 0; nf < 12; ++nf) {
            int ntg = nt0 + nf;
            if ((ntg >> 4) == c) {
                int cb = (ntg & 15) * 16 + lr;
#pragma unroll
                for (int mf = 0; mf < 2; ++mf)
#pragma unroll
                    for (int r = 0; r < 4; ++r)
                        smf[(mf * 16 + lk * 4 + r) * CLD2 + cb] = acc[mf][nf][r];
            }
        }
        __syncthreads();

        // epilogue: 16 tiles, 4 per wave
        if (c < 2) {
            // q or k: RoPE + pack-A
#pragma unroll
            for (int p = 0; p < 4; ++p) {
                int tile = w * 4 + p;
                int h = tile >> 2, mt = (tile >> 1) & 1, ktd = tile & 1;
                int row = mt * 16 + lr;
                int pos = pos0 + row;
                int d0 = ktd * 32 + lk * 8;
                const float* src = &smf[row * CLD2 + h * 64 + d0];
                BF8 o;
#pragma unroll
                for (int p2 = 0; p2 < 4; ++p2) {
                    float cs = cos_t[pos * IDIM + d0 + 2 * p2];
                    float sn = sin_t[pos * IDIM + d0 + 2 * p2];
                    float e = src[2 * p2], od = src[2 * p2 + 1];
                    o.u[2 * p2]     = f2bf(e * cs - od * sn);
                    o.u[2 * p2 + 1] = f2bf(od * cs + e * sn);
                }
                int sh = seq * 4 + h;
                int mtg = (pos0 >> 4) + mt;
                bf16x8s* dst = c ? ko : qo;
                dst[((size_t)sh * 32 + mtg * 2 + ktd) * 64 + l] = o.v;
            }
        } else {
            // v: pack-B over [kpos][d]
#pragma unroll
            for (int p = 0; p < 4; ++p) {
                int tile = w * 4 + p;
                int h = tile >> 2, ntd = tile & 3;
                BF8 o;
#pragma unroll
                for (int j = 0; j < 8; ++j)
                    o.u[j] = f2bf(smf[(lk * 8 + j) * CLD2 + h * 64 + ntd * 16 + lr]);
                int sh = seq * 4 + h;
                int ktg = pos0 >> 5;
                vo[((size_t)sh * 32 + ktg * 4 + ntd) * 64 + l] = o.v;
            }
        }
        __syncthreads();
    }
}

// =====================================================================
// Attention: block = (seq,head). 4 waves x 64 q-rows. Flash over 4 key-tiles of 64.
// P tile in LDS as bf16 with 16B XOR swizzle (byte ^= (row&7)<<4):
//   conflict-free b128 fragment reads, no f2bf on the PV path.
// =====================================================================
__global__ __launch_bounds__(256) void attn_kernel(
    const bf16x8s* __restrict__ qpk, const bf16x8s* __restrict__ kpk,
    const bf16x8s* __restrict__ vpk, bf16x8s* __restrict__ opk)
{
    __shared__ __align__(16) unsigned short Pus[4 * 64 * 64];   // 32,768 B
    char* Pb = (char*)Pus;
    const int tid = threadIdx.x, l = tid & 63, w = tid >> 6;
    const int lr = l & 15, lk = l >> 4;
    const int sh = blockIdx.x;
    const size_t base = (size_t)sh * 32 * 64;

    bf16x8s qf[4][2];
#pragma unroll
    for (int mf = 0; mf < 4; ++mf)
#pragma unroll
        for (int kt = 0; kt < 2; ++kt)
            qf[mf][kt] = qpk[base + ((size_t)((w * 4 + mf) * 2 + kt)) * 64 + l];

    f32x4 O[4][4];
    float mrun[4][4], lrun[4][4];
#pragma unroll
    for (int mf = 0; mf < 4; ++mf)
#pragma unroll
        for (int nf = 0; nf < 4; ++nf) { f32x4 z = {0.f, 0.f, 0.f, 0.f}; O[mf][nf] = z; }
#pragma unroll
    for (int mf = 0; mf < 4; ++mf)
#pragma unroll
        for (int r = 0; r < 4; ++r) { mrun[mf][r] = -1e30f; lrun[mf][r] = 0.f; }

    for (int ktk = 0; ktk < 4; ++ktk) {
        f32x4 S[4][4];
#pragma unroll
        for (int mf = 0; mf < 4; ++mf)
#pragma unroll
            for (int nf = 0; nf < 4; ++nf) { f32x4 z = {0.f, 0.f, 0.f, 0.f}; S[mf][nf] = z; }
#pragma unroll
        for (int ks = 0; ks < 2; ++ks) {
            bf16x8s kf[4];
#pragma unroll
            for (int nf = 0; nf < 4; ++nf)
                kf[nf] = kpk[base + ((size_t)((ktk * 4 + nf) * 2 + ks)) * 64 + l];
#pragma unroll
            for (int mf = 0; mf < 4; ++mf)
#pragma unroll
                for (int nf = 0; nf < 4; ++nf)
                    S[mf][nf] = __builtin_amdgcn_mfma_f32_16x16x32_bf16(qf[mf][ks], kf[nf], S[mf][nf], 0, 0, 0);
        }
        // online softmax per row
#pragma unroll
        for (int mf = 0; mf < 4; ++mf) {
#pragma unroll
            for (int r = 0; r < 4; ++r) {
                float mt_ = fmaxf(fmaxf(S[mf][0][r], S[mf][1][r]), fmaxf(S[mf][2][r], S[mf][3][r]));
                for (int off = 1; off < 16; off <<= 1) mt_ = fmaxf(mt_, __shfl_xor(mt_, off, 64));
                float mnew = fmaxf(mrun[mf][r], mt_);
                float sc = __expf(mrun[mf][r] - mnew);
#pragma unroll
                for (int nf = 0; nf < 4; ++nf) O[mf][nf][r] *= sc;
                float ps = 0.f;
#pragma unroll
                for (int nf = 0; nf < 4; ++nf) {
                    float pp = __expf(S[mf][nf][r] - mnew);
                    S[mf][nf][r] = pp;
                    ps += pp;
                }
                for (int off = 1; off < 16; off <<= 1) ps += __shfl_xor(ps, off, 64);
                lrun[mf][r] = lrun[mf][r] * sc + ps;
                mrun[mf][r] = mnew;
            }
        }
        // P -> LDS (bf16, swizzled)
#pragma unroll
        for (int mf = 0; mf < 4; ++mf)
#pragma unroll
            for (int nf = 0; nf < 4; ++nf)
#pragma unroll
                for (int r = 0; r < 4; ++r) {
                    int row = mf * 16 + lk * 4 + r, col = nf * 16 + lr;
                    unsigned int byte = ((unsigned)((w * 64 + row) * 64 + col) * 2) ^ (unsigned)((row & 7) << 4);
                    *(unsigned short*)(Pb + byte) = f2bf(S[mf][nf][r]);
                }
        __syncthreads();
#pragma unroll
        for (int ks = 0; ks < 2; ++ks) {
            bf16x8s vf[4];
#pragma unroll
            for (int nf = 0; nf < 4; ++nf)
                vf[nf] = vpk[base + ((size_t)((ktk * 2 + ks) * 4 + nf)) * 64 + l];
#pragma unroll
            for (int mf = 0; mf < 4; ++mf) {
                int row = mf * 16 + lr;
                unsigned int byte = ((unsigned)((w * 64 + row) * 64 + ks * 32 + lk * 8) * 2) ^ (unsigned)((row & 7) << 4);
                bf16x8s pa = *(const bf16x8s*)(Pb + byte);
#pragma unroll
                for (int nf = 0; nf < 4; ++nf)
                    O[mf][nf] = __builtin_amdgcn_mfma_f32_16x16x32_bf16(pa, vf[nf], O[mf][nf], 0, 0, 0);
            }
        }
        __syncthreads();
    }

    // normalize -> LDS (bf16, swizzled) -> pack out (h-major cols)
#pragma unroll
    for (int mf = 0; mf < 4; ++mf)
#pragma unroll
        for (int r = 0; r < 4; ++r) {
            float inv = 1.f / lrun[mf][r];
#pragma unroll
            for (int nf = 0; nf < 4; ++nf) {
                int row = mf * 16 + lk * 4 + r, col = nf * 16 + lr;
                unsigned int byte = ((unsigned)((w * 64 + row) * 64 + col) * 2) ^ (unsigned)((row & 7) << 4);
                *(unsigned short*)(Pb + byte) = f2bf(O[mf][nf][r] * inv);
            }
        }
    __syncthreads();
    const int seq = sh >> 2, h = sh & 3;
#pragma unroll
    for (int mf = 0; mf < 4; ++mf)
#pragma unroll
        for (int ktd = 0; ktd < 2; ++ktd) {
            int row = mf * 16 + lr;
            unsigned int byte = ((unsigned)((w * 64 + row) * 64 + ktd * 32 + lk * 8) * 2) ^ (unsigned)((row & 7) << 4);
            bf16x8s o = *(const bf16x8s*)(Pb + byte);
            size_t mtg = (size_t)seq * 16 + w * 4 + mf;
            opk[(mtg * 8 + h * 2 + ktd) * 64 + l] = o;
        }
}

// =====================================================================
// Proj GEMM: A = o_pk, B = g_wpk[pass*4+3]. Epilogue: bias+ELU+residual.
// C tile in LDS as bf16 [128][136].
// =====================================================================
__device__ __forceinline__ void gemm_core(
    const bf16x8s* __restrict__ A, const bf16x8s* __restrict__ B,
    int mt0, int nt0, int l, f32x4 acc[4][4])
{
#pragma unroll
    for (int mf = 0; mf < 4; ++mf)
#pragma unroll
        for (int nf = 0; nf < 4; ++nf) { f32x4 z = {0.f, 0.f, 0.f, 0.f}; acc[mf][nf] = z; }
#pragma unroll
    for (int ks = 0; ks < 8; ++ks) {
        bf16x8s a[4], b[4];
#pragma unroll
        for (int mf = 0; mf < 4; ++mf) a[mf] = A[((size_t)(mt0 + mf) * 8 + ks) * 64 + l];
#pragma unroll
        for (int nf = 0; nf < 4; ++nf) b[nf] = B[((size_t)(nt0 + nf) * 8 + ks) * 64 + l];
#pragma unroll
        for (int mf = 0; mf < 4; ++mf)
#pragma unroll
            for (int nf = 0; nf < 4; ++nf)
                acc[mf][nf] = __builtin_amdgcn_mfma_f32_16x16x32_bf16(a[mf], b[nf], acc[mf][nf], 0, 0, 0);
    }
}

__global__ __launch_bounds__(256, 4) void gemm_proj_kernel(
    const bf16x8s* __restrict__ A,
    const float* __restrict__ x, const float* __restrict__ bo,
    float* __restrict__ out, int pass)
{
    __shared__ unsigned short Cus[128][136];   // 34,816 B
    const int tid = threadIdx.x;
    const int l = tid & 63, w = tid >> 6;
    const int wm = w >> 1, wn = w & 1;
    const int mb = blockIdx.x, nb = blockIdx.y;

    f32x4 acc[4][4];
    gemm_core(A, g_wpk[pass * 4 + 3], mb * 8 + wm * 4, nb * 8 + wn * 4, l, acc);

#pragma unroll
    for (int mf = 0; mf < 4; ++mf)
#pragma unroll
        for (int nf = 0; nf < 4; ++nf)
#pragma unroll
            for (int r = 0; r < 4; ++r)
                Cus[wm * 64 + mf * 16 + (l >> 4) * 4 + r][wn * 64 + nf * 16 + (l & 15)] =
                    f2bf(acc[mf][nf][r]);
    __syncthreads();

    const int row = tid >> 1;
    const int cc0 = (tid & 1) * 64;
    const int tok = mb * 128 + row;
    const size_t prow = (pass == 0) ? (size_t)tok
                                    : ((size_t)(tok & 255) * NSEQ + (tok >> 8));
    const size_t gb = prow * DIM + nb * 128 + cc0;
#pragma unroll
    for (int qq = 0; qq < 16; ++qq) {
        float4 r4;
        const float4 b4 = *reinterpret_cast<const float4*>(&bo[nb * 128 + cc0 + qq * 4]);
        float y0 = bf2f(Cus[row][cc0 + qq * 4 + 0]) + b4.x;
        float y1 = bf2f(Cus[row][cc0 + qq * 4 + 1]) + b4.y;
        float y2 = bf2f(Cus[row][cc0 + qq * 4 + 2]) + b4.z;
        float y3 = bf2f(Cus[row][cc0 + qq * 4 + 3]) + b4.w;
        r4.x = 0.5f * (y0 > 0.f ? y0 : expm1f(y0));
        r4.y = 0.5f * (y1 > 0.f ? y1 : expm1f(y1));
        r4.z = 0.5f * (y2 > 0.f ? y2 : expm1f(y2));
        r4.w = 0.5f * (y3 > 0.f ? y3 : expm1f(y3));
        if (pass == 0) {
            const float4 x4 = *reinterpret_cast<const float4*>(&x[gb + qq * 4]);
            r4.x += x4.x; r4.y += x4.y; r4.z += x4.z; r4.w += x4.w;
            *reinterpret_cast<float4*>(&out[gb + qq * 4]) = r4;
        } else {
            float4* op = reinterpret_cast<float4*>(&out[gb + qq * 4]);
            float4 o4 = *op;
            o4.x += r4.x; o4.y += r4.y; o4.z += r4.z; o4.w += r4.w;
            *op = o4;
        }
    }
}

// =====================================================================
extern "C" void kernel_launch(void* const* d_in, const int* in_sizes, int n_in,
                              void* d_out, int out_size, void* d_ws, size_t ws_size,
                              hipStream_t stream) {
    const float* x     = (const float*)d_in[0];
    const float* sin_i = (const float*)d_in[1];
    const float* cos_i = (const float*)d_in[2];
    const float* sin_j = (const float*)d_in[3];
    const float* cos_j = (const float*)d_in[4];
    const float* gia   = (const float*)d_in[5];
    const float* bia   = (const float*)d_in[6];
    const float* gib   = (const float*)d_in[7];
    const float* bib   = (const float*)d_in[8];
    const float* Wq_i  = (const float*)d_in[9];
    const float* Wkv_i = (const float*)d_in[10];
    const float* Wo_i  = (const float*)d_in[11];
    const float* bo_i  = (const float*)d_in[12];
    const float* gja   = (const float*)d_in[13];
    const float* bja   = (const float*)d_in[14];
    const float* gjb   = (const float*)d_in[15];
    const float* bjb   = (const float*)d_in[16];
    const float* Wq_j  = (const float*)d_in[17];
    const float* Wkv_j = (const float*)d_in[18];
    const float* Wo_j  = (const float*)d_in[19];
    const float* bo_j  = (const float*)d_in[20];

    float* out = (float*)d_out;

    char* base = (char*)d_ws;
    const size_t MB32 = 33554432;
    bf16x8s* buf0 = (bf16x8s*)(base);             // v
    bf16x8s* buf1 = (bf16x8s*)(base + MB32);      // o
    bf16x8s* buf2 = (bf16x8s*)(base + 2 * MB32);  // q
    bf16x8s* buf3 = (bf16x8s*)(base + 3 * MB32);  // k

    // pack all 8 weight matrices once
    wpack_all_kernel<<<dim3(32, 8), 256, 0, stream>>>(Wq_i, Wkv_i, Wo_i, Wq_j, Wkv_j, Wo_j);

    for (int pass = 0; pass < 2; ++pass) {
        const float* sin_t = pass ? sin_j : sin_i;
        const float* cos_t = pass ? cos_j : cos_i;
        const float* ga = pass ? gja : gia;  const float* ba = pass ? bja : bia;
        const float* gb = pass ? gjb : gib;  const float* bb = pass ? bjb : bib;
        const float* bo = pass ? bo_j : bo_i;

        // fused LN + QKV + RoPE + repack: q->buf2, k->buf3, v->buf0
        lnqkv_kernel<<<2048, 256, 0, stream>>>(
            x, sin_t, cos_t, ga, ba, gb, bb, buf2, buf3, buf0, pass);
        // attn: q,k,v -> o (buf1)
        attn_kernel<<<1024, 256, 0, stream>>>(buf2, buf3, buf0, buf1);
        // proj + residual
        gemm_proj_kernel<<<dim3(512, 2), 256, 0, stream>>>(buf1, x, bo, out, pass);
    }
}

// Round 9
// 905.548 us; speedup vs baseline: 1.3681x; 1.3681x over previous
//
#include <hip/hip_runtime.h>
#include <math.h>

#define DIM    256
#define IDIM   64
#define HEADS  4
#define NSEQ   256
#define SEQLEN 256
#define NTOK   (NSEQ * SEQLEN)
#define EPSLN  1e-5f

typedef __attribute__((ext_vector_type(8))) short bf16x8s;
typedef __attribute__((ext_vector_type(4))) float f32x4;

union BF8 { bf16x8s v; unsigned short u[8]; };

__device__ __forceinline__ float bf2f(unsigned short u) {
    union { unsigned int i; float f; } v; v.i = ((unsigned int)u) << 16; return v.f;
}
__device__ __forceinline__ unsigned short f2bf(float f) {
    union { float f; unsigned int i; } v; v.f = f;
    unsigned int x = v.i;
    return (unsigned short)((x + 0x7fffu + ((x >> 16) & 1u)) >> 16);
}

// Packed weights: 8 slots (pass*4 + {wq,wk,wv,wo}), each [16 nt][8 kt][64 lanes] x bf16x8
__device__ bf16x8s g_wpk[8][8192];

// =====================================================================
// Pack ALL weights once. grid=(32,8): y = slot (pass*4+m).
// B-fragment layout: lane l holds B[k=kt*32+8*(l>>4)+j][n=nt*16+(l&15)]
// Wo (m=3): packed k index is h-major (h*64+d); source row is d-major (d*4+h).
// =====================================================================
__global__ __launch_bounds__(256) void wpack_all_kernel(
    const float* __restrict__ Wq_i, const float* __restrict__ Wkv_i,
    const float* __restrict__ Wo_i,
    const float* __restrict__ Wq_j, const float* __restrict__ Wkv_j,
    const float* __restrict__ Wo_j)
{
    const int slot = blockIdx.y;
    const int pass = slot >> 2, m = slot & 3;
    const float* W; int ldw, col0, perm;
    if (m == 0)      { W = pass ? Wq_j  : Wq_i;  ldw = 256; col0 = 0;   perm = 0; }
    else if (m == 1) { W = pass ? Wkv_j : Wkv_i; ldw = 512; col0 = 0;   perm = 0; }
    else if (m == 2) { W = pass ? Wkv_j : Wkv_i; ldw = 512; col0 = 256; perm = 0; }
    else             { W = pass ? Wo_j  : Wo_i;  ldw = 256; col0 = 0;   perm = 1; }

    const int gtile = blockIdx.x * 4 + (threadIdx.x >> 6);   // nt*8+kt, 128 tiles
    const int l = threadIdx.x & 63;
    const int nt = gtile >> 3, kt = gtile & 7;
    const int n = nt * 16 + (l & 15);
    const int k0 = kt * 32 + (l >> 4) * 8;
    BF8 o;
#pragma unroll
    for (int j = 0; j < 8; ++j) {
        int k = k0 + j;
        int src = perm ? ((k & 63) * 4 + (k >> 6)) : k;
        o.u[j] = f2bf(W[(size_t)src * ldw + col0 + n]);
    }
    g_wpk[slot][(size_t)gtile * 64 + l] = o.v;
}

// =====================================================================
// Fused LN + QKV GEMM (f32 activations, hi+lo bf16 MFMA) + RoPE + repack.
// Block = 32 tokens (one seq). 4 waves; wave w owns n-tiles [w*12, w*12+12).
// LDS 37.9 KB: phase1 xn[32][264]+params[1024]; phase2 C chunks 32x261 (q,k,v serially).
// NOTE: no min-waves in launch_bounds — (256,3) made the compiler cap VGPR at 84
// and spill acc[2][12] in the K-loop: 850 MB scratch writes/dispatch (round 7).
// =====================================================================
#define XLD  264
#define GOFF (32 * XLD)           // 8448
#define CLD2 261

__global__ __launch_bounds__(256) void lnqkv_kernel(
    const float* __restrict__ x,
    const float* __restrict__ sin_t, const float* __restrict__ cos_t,
    const float* __restrict__ ga, const float* __restrict__ ba,
    const float* __restrict__ gb, const float* __restrict__ bb,
    bf16x8s* __restrict__ qo, bf16x8s* __restrict__ ko, bf16x8s* __restrict__ vo,
    int pass)
{
    __shared__ float smf[32 * XLD + 1024];   // 37,888 B

    const int tid = threadIdx.x;
    const int l = tid & 63, w = tid >> 6;
    const int lr = l & 15, lk = l >> 4;
    const int t0 = blockIdx.x * 32;
    const int seq = t0 >> 8;
    const int pos0 = t0 & 255;
    const int wbase = pass * 4;

    // ---- stage x rows + LN params ----
    for (int r = 0; r < 32; ++r) {
        int t = t0 + r;
        int row = (pass == 0) ? t : ((t & 255) * NSEQ + (t >> 8));
        smf[r * XLD + tid] = x[(size_t)row * DIM + tid];
    }
    smf[GOFF + 0 * 256 + tid] = ga[tid];
    smf[GOFF + 1 * 256 + tid] = ba[tid];
    smf[GOFF + 2 * 256 + tid] = gb[tid];
    smf[GOFF + 3 * 256 + tid] = bb[tid];
    __syncthreads();

    // ---- LN stats (8 threads/row), normalize in place ----
    {
        const int r = tid >> 3, sub = tid & 7;
        float s1 = 0.f, s2 = 0.f;
        for (int m = 0; m < 32; ++m) { float v = smf[r * XLD + sub + 8 * m]; s1 += v; s2 += v * v; }
        for (int off = 1; off < 8; off <<= 1) {
            s1 += __shfl_xor(s1, off, 64);
            s2 += __shfl_xor(s2, off, 64);
        }
        float mu = s1 * (1.f / 256.f);
        float var = s2 * (1.f / 256.f) - mu * mu;
        float rstd = rsqrtf(var + EPSLN);
        for (int m = 0; m < 32; ++m) {
            int d = sub + 8 * m;
            smf[r * XLD + d] = (smf[r * XLD + d] - mu) * rstd;
        }
    }
    __syncthreads();

    // ---- K-loop: acc[2 m-frags][12 n-frags], hi+lo A ----
    f32x4 acc[2][12];
#pragma unroll
    for (int mf = 0; mf < 2; ++mf)
#pragma unroll
        for (int nf = 0; nf < 12; ++nf) { f32x4 z = {0.f, 0.f, 0.f, 0.f}; acc[mf][nf] = z; }

    const int nt0 = w * 12;
    const bool needA = (nt0 < 16);
    const bool needB = (nt0 + 11 >= 16);

    for (int ks = 0; ks < 8; ++ks) {
        const int c0 = ks * 32 + lk * 8;
        float gav[8], bav[8], gbv[8], bbv[8];
#pragma unroll
        for (int j = 0; j < 8; ++j) {
            gav[j] = smf[GOFF + 0 * 256 + c0 + j];
            bav[j] = smf[GOFF + 1 * 256 + c0 + j];
            gbv[j] = smf[GOFF + 2 * 256 + c0 + j];
            bbv[j] = smf[GOFF + 3 * 256 + c0 + j];
        }
        BF8 ahA[2], alA[2], ahB[2], alB[2];
#pragma unroll
        for (int mf = 0; mf < 2; ++mf) {
            const float* xr = &smf[(mf * 16 + lr) * XLD + c0];
            float xv[8];
#pragma unroll
            for (int j = 0; j < 8; ++j) xv[j] = xr[j];
            if (needA) {
#pragma unroll
                for (int j = 0; j < 8; ++j) {
                    float a = xv[j] * gav[j] + bav[j];
                    unsigned short hi = f2bf(a);
                    ahA[mf].u[j] = hi;
                    alA[mf].u[j] = f2bf(a - bf2f(hi));
                }
            }
            if (needB) {
#pragma unroll
                for (int j = 0; j < 8; ++j) {
                    float a = xv[j] * gbv[j] + bbv[j];
                    unsigned short hi = f2bf(a);
                    ahB[mf].u[j] = hi;
                    alB[mf].u[j] = f2bf(a - bf2f(hi));
                }
            }
        }
#pragma unroll
        for (int nf = 0; nf < 12; ++nf) {
            const int ntg = nt0 + nf;      // wave-uniform
            const bf16x8s b = g_wpk[wbase + (ntg >> 4)][((size_t)((ntg & 15) * 8 + ks)) * 64 + l];
            if (ntg < 16) {
#pragma unroll
                for (int mf = 0; mf < 2; ++mf) {
                    acc[mf][nf] = __builtin_amdgcn_mfma_f32_16x16x32_bf16(alA[mf].v, b, acc[mf][nf], 0, 0, 0);
                    acc[mf][nf] = __builtin_amdgcn_mfma_f32_16x16x32_bf16(ahA[mf].v, b, acc[mf][nf], 0, 0, 0);
                }
            } else {
#pragma unroll
                for (int mf = 0; mf < 2; ++mf) {
                    acc[mf][nf] = __builtin_amdgcn_mfma_f32_16x16x32_bf16(alB[mf].v, b, acc[mf][nf], 0, 0, 0);
                    acc[mf][nf] = __builtin_amdgcn_mfma_f32_16x16x32_bf16(ahB[mf].v, b, acc[mf][nf], 0, 0, 0);
                }
            }
        }
    }
    __syncthreads();   // all waves done reading xn/params

    // ---- three C chunks (q, k, v): write f32 C, then epilogue ----
    for (int c = 0; c < 3; ++c) {
        // write this wave's n-tiles belonging to chunk c
#pragma unroll
        for (int nf = 0; nf < 12; ++nf) {
            int ntg = nt0 + nf;
            if ((ntg >> 4) == c) {
                int cb = (ntg & 15) * 16 + lr;
#pragma unroll
                for (int mf = 0; mf < 2; ++mf)
#pragma unroll
                    for (int r = 0; r < 4; ++r)
                        smf[(mf * 16 + lk * 4 + r) * CLD2 + cb] = acc[mf][nf][r];
            }
        }
        __syncthreads();

        // epilogue: 16 tiles, 4 per wave
        if (c < 2) {
            // q or k: RoPE + pack-A
#pragma unroll
            for (int p = 0; p < 4; ++p) {
                int tile = w * 4 + p;
                int h = tile >> 2, mt = (tile >> 1) & 1, ktd = tile & 1;
                int row = mt * 16 + lr;
                int pos = pos0 + row;
                int d0 = ktd * 32 + lk * 8;
                const float* src = &smf[row * CLD2 + h * 64 + d0];
                BF8 o;
#pragma unroll
                for (int p2 = 0; p2 < 4; ++p2) {
                    float cs = cos_t[pos * IDIM + d0 + 2 * p2];
                    float sn = sin_t[pos * IDIM + d0 + 2 * p2];
                    float e = src[2 * p2], od = src[2 * p2 + 1];
                    o.u[2 * p2]     = f2bf(e * cs - od * sn);
                    o.u[2 * p2 + 1] = f2bf(od * cs + e * sn);
                }
                int sh = seq * 4 + h;
                int mtg = (pos0 >> 4) + mt;
                bf16x8s* dst = c ? ko : qo;
                dst[((size_t)sh * 32 + mtg * 2 + ktd) * 64 + l] = o.v;
            }
        } else {
            // v: pack-B over [kpos][d]
#pragma unroll
            for (int p = 0; p < 4; ++p) {
                int tile = w * 4 + p;
                int h = tile >> 2, ntd = tile & 3;
                BF8 o;
#pragma unroll
                for (int j = 0; j < 8; ++j)
                    o.u[j] = f2bf(smf[(lk * 8 + j) * CLD2 + h * 64 + ntd * 16 + lr]);
                int sh = seq * 4 + h;
                int ktg = pos0 >> 5;
                vo[((size_t)sh * 32 + ktg * 4 + ntd) * 64 + l] = o.v;
            }
        }
        __syncthreads();
    }
}

// =====================================================================
// Attention: block = (seq,head). 4 waves x 64 q-rows. Flash over 4 key-tiles of 64.
// P tile in LDS as bf16 with 16B XOR swizzle (byte ^= (row&7)<<4):
//   conflict-free b128 fragment reads, no f2bf on the PV path.
// =====================================================================
__global__ __launch_bounds__(256) void attn_kernel(
    const bf16x8s* __restrict__ qpk, const bf16x8s* __restrict__ kpk,
    const bf16x8s* __restrict__ vpk, bf16x8s* __restrict__ opk)
{
    __shared__ __align__(16) unsigned short Pus[4 * 64 * 64];   // 32,768 B
    char* Pb = (char*)Pus;
    const int tid = threadIdx.x, l = tid & 63, w = tid >> 6;
    const int lr = l & 15, lk = l >> 4;
    const int sh = blockIdx.x;
    const size_t base = (size_t)sh * 32 * 64;

    bf16x8s qf[4][2];
#pragma unroll
    for (int mf = 0; mf < 4; ++mf)
#pragma unroll
        for (int kt = 0; kt < 2; ++kt)
            qf[mf][kt] = qpk[base + ((size_t)((w * 4 + mf) * 2 + kt)) * 64 + l];

    f32x4 O[4][4];
    float mrun[4][4], lrun[4][4];
#pragma unroll
    for (int mf = 0; mf < 4; ++mf)
#pragma unroll
        for (int nf = 0; nf < 4; ++nf) { f32x4 z = {0.f, 0.f, 0.f, 0.f}; O[mf][nf] = z; }
#pragma unroll
    for (int mf = 0; mf < 4; ++mf)
#pragma unroll
        for (int r = 0; r < 4; ++r) { mrun[mf][r] = -1e30f; lrun[mf][r] = 0.f; }

    for (int ktk = 0; ktk < 4; ++ktk) {
        f32x4 S[4][4];
#pragma unroll
        for (int mf = 0; mf < 4; ++mf)
#pragma unroll
            for (int nf = 0; nf < 4; ++nf) { f32x4 z = {0.f, 0.f, 0.f, 0.f}; S[mf][nf] = z; }
#pragma unroll
        for (int ks = 0; ks < 2; ++ks) {
            bf16x8s kf[4];
#pragma unroll
            for (int nf = 0; nf < 4; ++nf)
                kf[nf] = kpk[base + ((size_t)((ktk * 4 + nf) * 2 + ks)) * 64 + l];
#pragma unroll
            for (int mf = 0; mf < 4; ++mf)
#pragma unroll
                for (int nf = 0; nf < 4; ++nf)
                    S[mf][nf] = __builtin_amdgcn_mfma_f32_16x16x32_bf16(qf[mf][ks], kf[nf], S[mf][nf], 0, 0, 0);
        }
        // online softmax per row
#pragma unroll
        for (int mf = 0; mf < 4; ++mf) {
#pragma unroll
            for (int r = 0; r < 4; ++r) {
                float mt_ = fmaxf(fmaxf(S[mf][0][r], S[mf][1][r]), fmaxf(S[mf][2][r], S[mf][3][r]));
                for (int off = 1; off < 16; off <<= 1) mt_ = fmaxf(mt_, __shfl_xor(mt_, off, 64));
                float mnew = fmaxf(mrun[mf][r], mt_);
                float sc = __expf(mrun[mf][r] - mnew);
#pragma unroll
                for (int nf = 0; nf < 4; ++nf) O[mf][nf][r] *= sc;
                float ps = 0.f;
#pragma unroll
                for (int nf = 0; nf < 4; ++nf) {
                    float pp = __expf(S[mf][nf][r] - mnew);
                    S[mf][nf][r] = pp;
                    ps += pp;
                }
                for (int off = 1; off < 16; off <<= 1) ps += __shfl_xor(ps, off, 64);
                lrun[mf][r] = lrun[mf][r] * sc + ps;
                mrun[mf][r] = mnew;
            }
        }
        // P -> LDS (bf16, swizzled)
#pragma unroll
        for (int mf = 0; mf < 4; ++mf)
#pragma unroll
            for (int nf = 0; nf < 4; ++nf)
#pragma unroll
                for (int r = 0; r < 4; ++r) {
                    int row = mf * 16 + lk * 4 + r, col = nf * 16 + lr;
                    unsigned int byte = ((unsigned)((w * 64 + row) * 64 + col) * 2) ^ (unsigned)((row & 7) << 4);
                    *(unsigned short*)(Pb + byte) = f2bf(S[mf][nf][r]);
                }
        __syncthreads();
#pragma unroll
        for (int ks = 0; ks < 2; ++ks) {
            bf16x8s vf[4];
#pragma unroll
            for (int nf = 0; nf < 4; ++nf)
                vf[nf] = vpk[base + ((size_t)((ktk * 2 + ks) * 4 + nf)) * 64 + l];
#pragma unroll
            for (int mf = 0; mf < 4; ++mf) {
                int row = mf * 16 + lr;
                unsigned int byte = ((unsigned)((w * 64 + row) * 64 + ks * 32 + lk * 8) * 2) ^ (unsigned)((row & 7) << 4);
                bf16x8s pa = *(const bf16x8s*)(Pb + byte);
#pragma unroll
                for (int nf = 0; nf < 4; ++nf)
                    O[mf][nf] = __builtin_amdgcn_mfma_f32_16x16x32_bf16(pa, vf[nf], O[mf][nf], 0, 0, 0);
            }
        }
        __syncthreads();
    }

    // normalize -> LDS (bf16, swizzled) -> pack out (h-major cols)
#pragma unroll
    for (int mf = 0; mf < 4; ++mf)
#pragma unroll
        for (int r = 0; r < 4; ++r) {
            float inv = 1.f / lrun[mf][r];
#pragma unroll
            for (int nf = 0; nf < 4; ++nf) {
                int row = mf * 16 + lk * 4 + r, col = nf * 16 + lr;
                unsigned int byte = ((unsigned)((w * 64 + row) * 64 + col) * 2) ^ (unsigned)((row & 7) << 4);
                *(unsigned short*)(Pb + byte) = f2bf(O[mf][nf][r] * inv);
            }
        }
    __syncthreads();
    const int seq = sh >> 2, h = sh & 3;
#pragma unroll
    for (int mf = 0; mf < 4; ++mf)
#pragma unroll
        for (int ktd = 0; ktd < 2; ++ktd) {
            int row = mf * 16 + lr;
            unsigned int byte = ((unsigned)((w * 64 + row) * 64 + ktd * 32 + lk * 8) * 2) ^ (unsigned)((row & 7) << 4);
            bf16x8s o = *(const bf16x8s*)(Pb + byte);
            size_t mtg = (size_t)seq * 16 + w * 4 + mf;
            opk[(mtg * 8 + h * 2 + ktd) * 64 + l] = o;
        }
}

// =====================================================================
// Proj GEMM: A = o_pk, B = g_wpk[pass*4+3]. Epilogue: bias+ELU+residual.
// C tile in LDS as bf16 [128][136].
// =====================================================================
__device__ __forceinline__ void gemm_core(
    const bf16x8s* __restrict__ A, const bf16x8s* __restrict__ B,
    int mt0, int nt0, int l, f32x4 acc[4][4])
{
#pragma unroll
    for (int mf = 0; mf < 4; ++mf)
#pragma unroll
        for (int nf = 0; nf < 4; ++nf) { f32x4 z = {0.f, 0.f, 0.f, 0.f}; acc[mf][nf] = z; }
#pragma unroll
    for (int ks = 0; ks < 8; ++ks) {
        bf16x8s a[4], b[4];
#pragma unroll
        for (int mf = 0; mf < 4; ++mf) a[mf] = A[((size_t)(mt0 + mf) * 8 + ks) * 64 + l];
#pragma unroll
        for (int nf = 0; nf < 4; ++nf) b[nf] = B[((size_t)(nt0 + nf) * 8 + ks) * 64 + l];
#pragma unroll
        for (int mf = 0; mf < 4; ++mf)
#pragma unroll
            for (int nf = 0; nf < 4; ++nf)
                acc[mf][nf] = __builtin_amdgcn_mfma_f32_16x16x32_bf16(a[mf], b[nf], acc[mf][nf], 0, 0, 0);
    }
}

__global__ __launch_bounds__(256) void gemm_proj_kernel(
    const bf16x8s* __restrict__ A,
    const float* __restrict__ x, const float* __restrict__ bo,
    float* __restrict__ out, int pass)
{
    __shared__ unsigned short Cus[128][136];   // 34,816 B
    const int tid = threadIdx.x;
    const int l = tid & 63, w = tid >> 6;
    const int wm = w >> 1, wn = w & 1;
    const int mb = blockIdx.x, nb = blockIdx.y;

    f32x4 acc[4][4];
    gemm_core(A, g_wpk[pass * 4 + 3], mb * 8 + wm * 4, nb * 8 + wn * 4, l, acc);

#pragma unroll
    for (int mf = 0; mf < 4; ++mf)
#pragma unroll
        for (int nf = 0; nf < 4; ++nf)
#pragma unroll
            for (int r = 0; r < 4; ++r)
                Cus[wm * 64 + mf * 16 + (l >> 4) * 4 + r][wn * 64 + nf * 16 + (l & 15)] =
                    f2bf(acc[mf][nf][r]);
    __syncthreads();

    const int row = tid >> 1;
    const int cc0 = (tid & 1) * 64;
    const int tok = mb * 128 + row;
    const size_t prow = (pass == 0) ? (size_t)tok
                                    : ((size_t)(tok & 255) * NSEQ + (tok >> 8));
    const size_t gb = prow * DIM + nb * 128 + cc0;
#pragma unroll
    for (int qq = 0; qq < 16; ++qq) {
        float4 r4;
        const float4 b4 = *reinterpret_cast<const float4*>(&bo[nb * 128 + cc0 + qq * 4]);
        float y0 = bf2f(Cus[row][cc0 + qq * 4 + 0]) + b4.x;
        float y1 = bf2f(Cus[row][cc0 + qq * 4 + 1]) + b4.y;
        float y2 = bf2f(Cus[row][cc0 + qq * 4 + 2]) + b4.z;
        float y3 = bf2f(Cus[row][cc0 + qq * 4 + 3]) + b4.w;
        r4.x = 0.5f * (y0 > 0.f ? y0 : expm1f(y0));
        r4.y = 0.5f * (y1 > 0.f ? y1 : expm1f(y1));
        r4.z = 0.5f * (y2 > 0.f ? y2 : expm1f(y2));
        r4.w = 0.5f * (y3 > 0.f ? y3 : expm1f(y3));
        if (pass == 0) {
            const float4 x4 = *reinterpret_cast<const float4*>(&x[gb + qq * 4]);
            r4.x += x4.x; r4.y += x4.y; r4.z += x4.z; r4.w += x4.w;
            *reinterpret_cast<float4*>(&out[gb + qq * 4]) = r4;
        } else {
            float4* op = reinterpret_cast<float4*>(&out[gb + qq * 4]);
            float4 o4 = *op;
            o4.x += r4.x; o4.y += r4.y; o4.z += r4.z; o4.w += r4.w;
            *op = o4;
        }
    }
}

// =====================================================================
extern "C" void kernel_launch(void* const* d_in, const int* in_sizes, int n_in,
                              void* d_out, int out_size, void* d_ws, size_t ws_size,
                              hipStream_t stream) {
    const float* x     = (const float*)d_in[0];
    const float* sin_i = (const float*)d_in[1];
    const float* cos_i = (const float*)d_in[2];
    const float* sin_j = (const float*)d_in[3];
    const float* cos_j = (const float*)d_in[4];
    const float* gia   = (const float*)d_in[5];
    const float* bia   = (const float*)d_in[6];
    const float* gib   = (const float*)d_in[7];
    const float* bib   = (const float*)d_in[8];
    const float* Wq_i  = (const float*)d_in[9];
    const float* Wkv_i = (const float*)d_in[10];
    const float* Wo_i  = (const float*)d_in[11];
    const float* bo_i  = (const float*)d_in[12];
    const float* gja   = (const float*)d_in[13];
    const float* bja   = (const float*)d_in[14];
    const float* gjb   = (const float*)d_in[15];
    const float* bjb   = (const float*)d_in[16];
    const float* Wq_j  = (const float*)d_in[17];
    const float* Wkv_j = (const float*)d_in[18];
    const float* Wo_j  = (const float*)d_in[19];
    const float* bo_j  = (const float*)d_in[20];

    float* out = (float*)d_out;

    char* base = (char*)d_ws;
    const size_t MB32 = 33554432;
    bf16x8s* buf0 = (bf16x8s*)(base);             // v
    bf16x8s* buf1 = (bf16x8s*)(base + MB32);      // o
    bf16x8s* buf2 = (bf16x8s*)(base + 2 * MB32);  // q
    bf16x8s* buf3 = (bf16x8s*)(base + 3 * MB32);  // k

    // pack all 8 weight matrices once
    wpack_all_kernel<<<dim3(32, 8), 256, 0, stream>>>(Wq_i, Wkv_i, Wo_i, Wq_j, Wkv_j, Wo_j);

    for (int pass = 0; pass < 2; ++pass) {
        const float* sin_t = pass ? sin_j : sin_i;
        const float* cos_t = pass ? cos_j : cos_i;
        const float* ga = pass ? gja : gia;  const float* ba = pass ? bja : bia;
        const float* gb = pass ? gjb : gib;  const float* bb = pass ? bjb : bib;
        const float* bo = pass ? bo_j : bo_i;

        // fused LN + QKV + RoPE + repack: q->buf2, k->buf3, v->buf0
        lnqkv_kernel<<<2048, 256, 0, stream>>>(
            x, sin_t, cos_t, ga, ba, gb, bb, buf2, buf3, buf0, pass);
        // attn: q,k,v -> o (buf1)
        attn_kernel<<<1024, 256, 0, stream>>>(buf2, buf3, buf0, buf1);
        // proj + residual
        gemm_proj_kernel<<<dim3(512, 2), 256, 0, stream>>>(buf1, x, bo, out, pass);
    }
}

// Round 10
// 638.901 us; speedup vs baseline: 1.9390x; 1.4174x over previous
//
#include <hip/hip_runtime.h>
#include <math.h>

#define DIM    256
#define IDIM   64
#define HEADS  4
#define NSEQ   256
#define SEQLEN 256
#define NTOK   (NSEQ * SEQLEN)
#define EPSLN  1e-5f

typedef __attribute__((ext_vector_type(8))) short bf16x8s;
typedef __attribute__((ext_vector_type(4))) float f32x4;

union BF8 { bf16x8s v; unsigned short u[8]; };

__device__ __forceinline__ float bf2f(unsigned short u) {
    union { unsigned int i; float f; } v; v.i = ((unsigned int)u) << 16; return v.f;
}
__device__ __forceinline__ unsigned short f2bf(float f) {
    union { float f; unsigned int i; } v; v.f = f;
    unsigned int x = v.i;
    return (unsigned short)((x + 0x7fffu + ((x >> 16) & 1u)) >> 16);
}

// Packed weights: 8 slots (pass*4 + {wq,wk,wv,wo}), each [16 nt][8 kt][64 lanes] x bf16x8
__device__ bf16x8s g_wpk[8][8192];

// =====================================================================
// Pack ALL weights once. grid=(32,8): y = slot (pass*4+m).
// =====================================================================
__global__ __launch_bounds__(256) void wpack_all_kernel(
    const float* __restrict__ Wq_i, const float* __restrict__ Wkv_i,
    const float* __restrict__ Wo_i,
    const float* __restrict__ Wq_j, const float* __restrict__ Wkv_j,
    const float* __restrict__ Wo_j)
{
    const int slot = blockIdx.y;
    const int pass = slot >> 2, m = slot & 3;
    const float* W; int ldw, col0, perm;
    if (m == 0)      { W = pass ? Wq_j  : Wq_i;  ldw = 256; col0 = 0;   perm = 0; }
    else if (m == 1) { W = pass ? Wkv_j : Wkv_i; ldw = 512; col0 = 0;   perm = 0; }
    else if (m == 2) { W = pass ? Wkv_j : Wkv_i; ldw = 512; col0 = 256; perm = 0; }
    else             { W = pass ? Wo_j  : Wo_i;  ldw = 256; col0 = 0;   perm = 1; }

    const int gtile = blockIdx.x * 4 + (threadIdx.x >> 6);   // nt*8+kt, 128 tiles
    const int l = threadIdx.x & 63;
    const int nt = gtile >> 3, kt = gtile & 7;
    const int n = nt * 16 + (l & 15);
    const int k0 = kt * 32 + (l >> 4) * 8;
    BF8 o;
#pragma unroll
    for (int j = 0; j < 8; ++j) {
        int k = k0 + j;
        int src = perm ? ((k & 63) * 4 + (k >> 6)) : k;
        o.u[j] = f2bf(W[(size_t)src * ldw + col0 + n]);
    }
    g_wpk[slot][(size_t)gtile * 64 + l] = o.v;
}

// =====================================================================
// Fused LN + QKV GEMM (f32 activations, hi+lo bf16 MFMA) + RoPE + repack.
// 512 threads (8 waves), block = 32 tokens; wave w owns n-tiles [w*6, w*6+6).
// acc[2][6] = 48 VGPR (vs 96 at 4 waves) -> target <=128 VGPR for 4 waves/SIMD.
// A-set / B-set fragments built in disjoint scopes to let regalloc reuse.
// LDS 37.9 KB unchanged.
// =====================================================================
#define XLD  264
#define GOFF (32 * XLD)           // 8448 floats
#define CLD2 261

__global__ __launch_bounds__(512) void lnqkv_kernel(
    const float* __restrict__ x,
    const float* __restrict__ sin_t, const float* __restrict__ cos_t,
    const float* __restrict__ ga, const float* __restrict__ ba,
    const float* __restrict__ gb, const float* __restrict__ bb,
    bf16x8s* __restrict__ qo, bf16x8s* __restrict__ ko, bf16x8s* __restrict__ vo,
    int pass)
{
    __shared__ float smf[32 * XLD + 1024];   // 37,888 B

    const int tid = threadIdx.x;
    const int l = tid & 63, w = tid >> 6;      // w 0..7
    const int lr = l & 15, lk = l >> 4;
    const int t0 = blockIdx.x * 32;
    const int seq = t0 >> 8;
    const int pos0 = t0 & 255;
    const int wbase = pass * 4;

    // ---- stage x rows (2 half-blocks of threads x 16 rows) + LN params ----
    {
        const int half = tid >> 8;       // 0/1
        const int col  = tid & 255;
        for (int rr = 0; rr < 16; ++rr) {
            int r = rr + 16 * half;
            int t = t0 + r;
            int row = (pass == 0) ? t : ((t & 255) * NSEQ + (t >> 8));
            smf[r * XLD + col] = x[(size_t)row * DIM + col];
        }
        smf[GOFF + tid]       = (tid < 256) ? ga[tid] : ba[tid - 256];
        smf[GOFF + 512 + tid] = (tid < 256) ? gb[tid] : bb[tid - 256];
    }
    __syncthreads();

    // ---- LN: 16 threads/row, normalize in place ----
    {
        const int r = tid >> 4, sub = tid & 15;
        float s1 = 0.f, s2 = 0.f;
        for (int m = 0; m < 16; ++m) { float v = smf[r * XLD + sub + 16 * m]; s1 += v; s2 += v * v; }
        for (int off = 1; off < 16; off <<= 1) {
            s1 += __shfl_xor(s1, off, 64);
            s2 += __shfl_xor(s2, off, 64);
        }
        float mu = s1 * (1.f / 256.f);
        float var = s2 * (1.f / 256.f) - mu * mu;
        float rstd = rsqrtf(var + EPSLN);
        for (int m = 0; m < 16; ++m) {
            int d = sub + 16 * m;
            smf[r * XLD + d] = (smf[r * XLD + d] - mu) * rstd;
        }
    }
    __syncthreads();

    // ---- K-loop: acc[2 m-frags][6 n-frags], hi+lo A, per-set scoped ----
    f32x4 acc[2][6];
#pragma unroll
    for (int mf = 0; mf < 2; ++mf)
#pragma unroll
        for (int nf = 0; nf < 6; ++nf) { f32x4 z = {0.f, 0.f, 0.f, 0.f}; acc[mf][nf] = z; }

    const int nt0 = w * 6;
    const bool needA = (nt0 < 16);          // waves 0,1,2
    const bool needB = (nt0 + 5 >= 16);     // waves 2..7

    for (int ks = 0; ks < 8; ++ks) {
        const int c0 = ks * 32 + lk * 8;
        if (needA) {
            BF8 ah[2], al[2];
#pragma unroll
            for (int mf = 0; mf < 2; ++mf) {
                const float* xr = &smf[(mf * 16 + lr) * XLD + c0];
                const float* gg = &smf[GOFF + c0];
                const float* bv = &smf[GOFF + 256 + c0];
#pragma unroll
                for (int j = 0; j < 8; ++j) {
                    float a = xr[j] * gg[j] + bv[j];
                    unsigned short hi = f2bf(a);
                    ah[mf].u[j] = hi;
                    al[mf].u[j] = f2bf(a - bf2f(hi));
                }
            }
#pragma unroll
            for (int nf = 0; nf < 6; ++nf) {
                int ntg = nt0 + nf;
                if (ntg < 16) {
                    const bf16x8s b = g_wpk[wbase][((size_t)(ntg * 8 + ks)) * 64 + l];
#pragma unroll
                    for (int mf = 0; mf < 2; ++mf) {
                        acc[mf][nf] = __builtin_amdgcn_mfma_f32_16x16x32_bf16(al[mf].v, b, acc[mf][nf], 0, 0, 0);
                        acc[mf][nf] = __builtin_amdgcn_mfma_f32_16x16x32_bf16(ah[mf].v, b, acc[mf][nf], 0, 0, 0);
                    }
                }
            }
        }
        if (needB) {
            BF8 ah[2], al[2];
#pragma unroll
            for (int mf = 0; mf < 2; ++mf) {
                const float* xr = &smf[(mf * 16 + lr) * XLD + c0];
                const float* gg = &smf[GOFF + 512 + c0];
                const float* bv = &smf[GOFF + 768 + c0];
#pragma unroll
                for (int j = 0; j < 8; ++j) {
                    float a = xr[j] * gg[j] + bv[j];
                    unsigned short hi = f2bf(a);
                    ah[mf].u[j] = hi;
                    al[mf].u[j] = f2bf(a - bf2f(hi));
                }
            }
#pragma unroll
            for (int nf = 0; nf < 6; ++nf) {
                int ntg = nt0 + nf;
                if (ntg >= 16) {
                    const bf16x8s b = g_wpk[wbase + (ntg >> 4)][((size_t)((ntg & 15) * 8 + ks)) * 64 + l];
#pragma unroll
                    for (int mf = 0; mf < 2; ++mf) {
                        acc[mf][nf] = __builtin_amdgcn_mfma_f32_16x16x32_bf16(al[mf].v, b, acc[mf][nf], 0, 0, 0);
                        acc[mf][nf] = __builtin_amdgcn_mfma_f32_16x16x32_bf16(ah[mf].v, b, acc[mf][nf], 0, 0, 0);
                    }
                }
            }
        }
    }
    __syncthreads();   // all waves done reading xn/params

    // ---- three C chunks (q, k, v): write f32 C, then epilogue ----
    for (int c = 0; c < 3; ++c) {
#pragma unroll
        for (int nf = 0; nf < 6; ++nf) {
            int ntg = nt0 + nf;
            if ((ntg >> 4) == c) {
                int cb = (ntg & 15) * 16 + lr;
#pragma unroll
                for (int mf = 0; mf < 2; ++mf)
#pragma unroll
                    for (int r = 0; r < 4; ++r)
                        smf[(mf * 16 + lk * 4 + r) * CLD2 + cb] = acc[mf][nf][r];
            }
        }
        __syncthreads();

        // epilogue: 16 tiles, 2 per wave
        if (c < 2) {
            // q or k: RoPE + pack-A
#pragma unroll
            for (int p = 0; p < 2; ++p) {
                int tile = w * 2 + p;
                int h = tile >> 2, mt = (tile >> 1) & 1, ktd = tile & 1;
                int row = mt * 16 + lr;
                int pos = pos0 + row;
                int d0 = ktd * 32 + lk * 8;
                const float* src = &smf[row * CLD2 + h * 64 + d0];
                BF8 o;
#pragma unroll
                for (int p2 = 0; p2 < 4; ++p2) {
                    float cs = cos_t[pos * IDIM + d0 + 2 * p2];
                    float sn = sin_t[pos * IDIM + d0 + 2 * p2];
                    float e = src[2 * p2], od = src[2 * p2 + 1];
                    o.u[2 * p2]     = f2bf(e * cs - od * sn);
                    o.u[2 * p2 + 1] = f2bf(od * cs + e * sn);
                }
                int sh = seq * 4 + h;
                int mtg = (pos0 >> 4) + mt;
                bf16x8s* dst = c ? ko : qo;
                dst[((size_t)sh * 32 + mtg * 2 + ktd) * 64 + l] = o.v;
            }
        } else {
            // v: pack-B over [kpos][d]
#pragma unroll
            for (int p = 0; p < 2; ++p) {
                int tile = w * 2 + p;
                int h = tile >> 2, ntd = tile & 3;
                BF8 o;
#pragma unroll
                for (int j = 0; j < 8; ++j)
                    o.u[j] = f2bf(smf[(lk * 8 + j) * CLD2 + h * 64 + ntd * 16 + lr]);
                int sh = seq * 4 + h;
                int ktg = pos0 >> 5;
                vo[((size_t)sh * 32 + ktg * 4 + ntd) * 64 + l] = o.v;
            }
        }
        __syncthreads();
    }
}

// =====================================================================
// Attention: block = (seq,head). 4 waves x 64 q-rows. Flash over 4 key-tiles of 64.
// P tile in LDS as bf16 with 16B XOR swizzle (byte ^= (row&7)<<4).
// =====================================================================
__global__ __launch_bounds__(256) void attn_kernel(
    const bf16x8s* __restrict__ qpk, const bf16x8s* __restrict__ kpk,
    const bf16x8s* __restrict__ vpk, bf16x8s* __restrict__ opk)
{
    __shared__ __align__(16) unsigned short Pus[4 * 64 * 64];   // 32,768 B
    char* Pb = (char*)Pus;
    const int tid = threadIdx.x, l = tid & 63, w = tid >> 6;
    const int lr = l & 15, lk = l >> 4;
    const int sh = blockIdx.x;
    const size_t base = (size_t)sh * 32 * 64;

    bf16x8s qf[4][2];
#pragma unroll
    for (int mf = 0; mf < 4; ++mf)
#pragma unroll
        for (int kt = 0; kt < 2; ++kt)
            qf[mf][kt] = qpk[base + ((size_t)((w * 4 + mf) * 2 + kt)) * 64 + l];

    f32x4 O[4][4];
    float mrun[4][4], lrun[4][4];
#pragma unroll
    for (int mf = 0; mf < 4; ++mf)
#pragma unroll
        for (int nf = 0; nf < 4; ++nf) { f32x4 z = {0.f, 0.f, 0.f, 0.f}; O[mf][nf] = z; }
#pragma unroll
    for (int mf = 0; mf < 4; ++mf)
#pragma unroll
        for (int r = 0; r < 4; ++r) { mrun[mf][r] = -1e30f; lrun[mf][r] = 0.f; }

    for (int ktk = 0; ktk < 4; ++ktk) {
        f32x4 S[4][4];
#pragma unroll
        for (int mf = 0; mf < 4; ++mf)
#pragma unroll
            for (int nf = 0; nf < 4; ++nf) { f32x4 z = {0.f, 0.f, 0.f, 0.f}; S[mf][nf] = z; }
#pragma unroll
        for (int ks = 0; ks < 2; ++ks) {
            bf16x8s kf[4];
#pragma unroll
            for (int nf = 0; nf < 4; ++nf)
                kf[nf] = kpk[base + ((size_t)((ktk * 4 + nf) * 2 + ks)) * 64 + l];
#pragma unroll
            for (int mf = 0; mf < 4; ++mf)
#pragma unroll
                for (int nf = 0; nf < 4; ++nf)
                    S[mf][nf] = __builtin_amdgcn_mfma_f32_16x16x32_bf16(qf[mf][ks], kf[nf], S[mf][nf], 0, 0, 0);
        }
        // online softmax per row
#pragma unroll
        for (int mf = 0; mf < 4; ++mf) {
#pragma unroll
            for (int r = 0; r < 4; ++r) {
                float mt_ = fmaxf(fmaxf(S[mf][0][r], S[mf][1][r]), fmaxf(S[mf][2][r], S[mf][3][r]));
                for (int off = 1; off < 16; off <<= 1) mt_ = fmaxf(mt_, __shfl_xor(mt_, off, 64));
                float mnew = fmaxf(mrun[mf][r], mt_);
                float sc = __expf(mrun[mf][r] - mnew);
#pragma unroll
                for (int nf = 0; nf < 4; ++nf) O[mf][nf][r] *= sc;
                float ps = 0.f;
#pragma unroll
                for (int nf = 0; nf < 4; ++nf) {
                    float pp = __expf(S[mf][nf][r] - mnew);
                    S[mf][nf][r] = pp;
                    ps += pp;
                }
                for (int off = 1; off < 16; off <<= 1) ps += __shfl_xor(ps, off, 64);
                lrun[mf][r] = lrun[mf][r] * sc + ps;
                mrun[mf][r] = mnew;
            }
        }
        // P -> LDS (bf16, swizzled)
#pragma unroll
        for (int mf = 0; mf < 4; ++mf)
#pragma unroll
            for (int nf = 0; nf < 4; ++nf)
#pragma unroll
                for (int r = 0; r < 4; ++r) {
                    int row = mf * 16 + lk * 4 + r, col = nf * 16 + lr;
                    unsigned int byte = ((unsigned)((w * 64 + row) * 64 + col) * 2) ^ (unsigned)((row & 7) << 4);
                    *(unsigned short*)(Pb + byte) = f2bf(S[mf][nf][r]);
                }
        __syncthreads();
#pragma unroll
        for (int ks = 0; ks < 2; ++ks) {
            bf16x8s vf[4];
#pragma unroll
            for (int nf = 0; nf < 4; ++nf)
                vf[nf] = vpk[base + ((size_t)((ktk * 2 + ks) * 4 + nf)) * 64 + l];
#pragma unroll
            for (int mf = 0; mf < 4; ++mf) {
                int row = mf * 16 + lr;
                unsigned int byte = ((unsigned)((w * 64 + row) * 64 + ks * 32 + lk * 8) * 2) ^ (unsigned)((row & 7) << 4);
                bf16x8s pa = *(const bf16x8s*)(Pb + byte);
#pragma unroll
                for (int nf = 0; nf < 4; ++nf)
                    O[mf][nf] = __builtin_amdgcn_mfma_f32_16x16x32_bf16(pa, vf[nf], O[mf][nf], 0, 0, 0);
            }
        }
        __syncthreads();
    }

    // normalize -> LDS (bf16, swizzled) -> pack out (h-major cols)
#pragma unroll
    for (int mf = 0; mf < 4; ++mf)
#pragma unroll
        for (int r = 0; r < 4; ++r) {
            float inv = 1.f / lrun[mf][r];
#pragma unroll
            for (int nf = 0; nf < 4; ++nf) {
                int row = mf * 16 + lk * 4 + r, col = nf * 16 + lr;
                unsigned int byte = ((unsigned)((w * 64 + row) * 64 + col) * 2) ^ (unsigned)((row & 7) << 4);
                *(unsigned short*)(Pb + byte) = f2bf(O[mf][nf][r] * inv);
            }
        }
    __syncthreads();
    const int seq = sh >> 2, h = sh & 3;
#pragma unroll
    for (int mf = 0; mf < 4; ++mf)
#pragma unroll
        for (int ktd = 0; ktd < 2; ++ktd) {
            int row = mf * 16 + lr;
            unsigned int byte = ((unsigned)((w * 64 + row) * 64 + ktd * 32 + lk * 8) * 2) ^ (unsigned)((row & 7) << 4);
            bf16x8s o = *(const bf16x8s*)(Pb + byte);
            size_t mtg = (size_t)seq * 16 + w * 4 + mf;
            opk[(mtg * 8 + h * 2 + ktd) * 64 + l] = o;
        }
}

// =====================================================================
// Proj GEMM: A = o_pk, B = g_wpk[pass*4+3]. Epilogue: bias+ELU+residual.
// =====================================================================
__device__ __forceinline__ void gemm_core(
    const bf16x8s* __restrict__ A, const bf16x8s* __restrict__ B,
    int mt0, int nt0, int l, f32x4 acc[4][4])
{
#pragma unroll
    for (int mf = 0; mf < 4; ++mf)
#pragma unroll
        for (int nf = 0; nf < 4; ++nf) { f32x4 z = {0.f, 0.f, 0.f, 0.f}; acc[mf][nf] = z; }
#pragma unroll
    for (int ks = 0; ks < 8; ++ks) {
        bf16x8s a[4], b[4];
#pragma unroll
        for (int mf = 0; mf < 4; ++mf) a[mf] = A[((size_t)(mt0 + mf) * 8 + ks) * 64 + l];
#pragma unroll
        for (int nf = 0; nf < 4; ++nf) b[nf] = B[((size_t)(nt0 + nf) * 8 + ks) * 64 + l];
#pragma unroll
        for (int mf = 0; mf < 4; ++mf)
#pragma unroll
            for (int nf = 0; nf < 4; ++nf)
                acc[mf][nf] = __builtin_amdgcn_mfma_f32_16x16x32_bf16(a[mf], b[nf], acc[mf][nf], 0, 0, 0);
    }
}

__global__ __launch_bounds__(256) void gemm_proj_kernel(
    const bf16x8s* __restrict__ A,
    const float* __restrict__ x, const float* __restrict__ bo,
    float* __restrict__ out, int pass)
{
    __shared__ unsigned short Cus[128][136];   // 34,816 B
    const int tid = threadIdx.x;
    const int l = tid & 63, w = tid >> 6;
    const int wm = w >> 1, wn = w & 1;
    const int mb = blockIdx.x, nb = blockIdx.y;

    f32x4 acc[4][4];
    gemm_core(A, g_wpk[pass * 4 + 3], mb * 8 + wm * 4, nb * 8 + wn * 4, l, acc);

#pragma unroll
    for (int mf = 0; mf < 4; ++mf)
#pragma unroll
        for (int nf = 0; nf < 4; ++nf)
#pragma unroll
            for (int r = 0; r < 4; ++r)
                Cus[wm * 64 + mf * 16 + (l >> 4) * 4 + r][wn * 64 + nf * 16 + (l & 15)] =
                    f2bf(acc[mf][nf][r]);
    __syncthreads();

    const int row = tid >> 1;
    const int cc0 = (tid & 1) * 64;
    const int tok = mb * 128 + row;
    const size_t prow = (pass == 0) ? (size_t)tok
                                    : ((size_t)(tok & 255) * NSEQ + (tok >> 8));
    const size_t gb = prow * DIM + nb * 128 + cc0;
#pragma unroll
    for (int qq = 0; qq < 16; ++qq) {
        float4 r4;
        const float4 b4 = *reinterpret_cast<const float4*>(&bo[nb * 128 + cc0 + qq * 4]);
        float y0 = bf2f(Cus[row][cc0 + qq * 4 + 0]) + b4.x;
        float y1 = bf2f(Cus[row][cc0 + qq * 4 + 1]) + b4.y;
        float y2 = bf2f(Cus[row][cc0 + qq * 4 + 2]) + b4.z;
        float y3 = bf2f(Cus[row][cc0 + qq * 4 + 3]) + b4.w;
        r4.x = 0.5f * (y0 > 0.f ? y0 : expm1f(y0));
        r4.y = 0.5f * (y1 > 0.f ? y1 : expm1f(y1));
        r4.z = 0.5f * (y2 > 0.f ? y2 : expm1f(y2));
        r4.w = 0.5f * (y3 > 0.f ? y3 : expm1f(y3));
        if (pass == 0) {
            const float4 x4 = *reinterpret_cast<const float4*>(&x[gb + qq * 4]);
            r4.x += x4.x; r4.y += x4.y; r4.z += x4.z; r4.w += x4.w;
            *reinterpret_cast<float4*>(&out[gb + qq * 4]) = r4;
        } else {
            float4* op = reinterpret_cast<float4*>(&out[gb + qq * 4]);
            float4 o4 = *op;
            o4.x += r4.x; o4.y += r4.y; o4.z += r4.z; o4.w += r4.w;
            *op = o4;
        }
    }
}

// =====================================================================
extern "C" void kernel_launch(void* const* d_in, const int* in_sizes, int n_in,
                              void* d_out, int out_size, void* d_ws, size_t ws_size,
                              hipStream_t stream) {
    const float* x     = (const float*)d_in[0];
    const float* sin_i = (const float*)d_in[1];
    const float* cos_i = (const float*)d_in[2];
    const float* sin_j = (const float*)d_in[3];
    const float* cos_j = (const float*)d_in[4];
    const float* gia   = (const float*)d_in[5];
    const float* bia   = (const float*)d_in[6];
    const float* gib   = (const float*)d_in[7];
    const float* bib   = (const float*)d_in[8];
    const float* Wq_i  = (const float*)d_in[9];
    const float* Wkv_i = (const float*)d_in[10];
    const float* Wo_i  = (const float*)d_in[11];
    const float* bo_i  = (const float*)d_in[12];
    const float* gja   = (const float*)d_in[13];
    const float* bja   = (const float*)d_in[14];
    const float* gjb   = (const float*)d_in[15];
    const float* bjb   = (const float*)d_in[16];
    const float* Wq_j  = (const float*)d_in[17];
    const float* Wkv_j = (const float*)d_in[18];
    const float* Wo_j  = (const float*)d_in[19];
    const float* bo_j  = (const float*)d_in[20];

    float* out = (float*)d_out;

    char* base = (char*)d_ws;
    const size_t MB32 = 33554432;
    bf16x8s* buf0 = (bf16x8s*)(base);             // v
    bf16x8s* buf1 = (bf16x8s*)(base + MB32);      // o
    bf16x8s* buf2 = (bf16x8s*)(base + 2 * MB32);  // q
    bf16x8s* buf3 = (bf16x8s*)(base + 3 * MB32);  // k

    // pack all 8 weight matrices once
    wpack_all_kernel<<<dim3(32, 8), 256, 0, stream>>>(Wq_i, Wkv_i, Wo_i, Wq_j, Wkv_j, Wo_j);

    for (int pass = 0; pass < 2; ++pass) {
        const float* sin_t = pass ? sin_j : sin_i;
        const float* cos_t = pass ? cos_j : cos_i;
        const float* ga = pass ? gja : gia;  const float* ba = pass ? bja : bia;
        const float* gb = pass ? gjb : gib;  const float* bb = pass ? bjb : bib;
        const float* bo = pass ? bo_j : bo_i;

        // fused LN + QKV + RoPE + repack: q->buf2, k->buf3, v->buf0
        lnqkv_kernel<<<2048, 512, 0, stream>>>(
            x, sin_t, cos_t, ga, ba, gb, bb, buf2, buf3, buf0, pass);
        // attn: q,k,v -> o (buf1)
        attn_kernel<<<1024, 256, 0, stream>>>(buf2, buf3, buf0, buf1);
        // proj + residual
        gemm_proj_kernel<<<dim3(512, 2), 256, 0, stream>>>(buf1, x, bo, out, pass);
    }
}